// Round 6
// baseline (748.254 us; speedup 1.0000x reference)
//
#include <hip/hip_runtime.h>

#define BB 512
#define LL 1024
#define DD 16
#define HH 64
#define CH 16     // timesteps per chunk
#define NB 16     // batches per tile (MFMA N)

typedef _Float16 half8 __attribute__((ext_vector_type(8)));
typedef float    f32x4 __attribute__((ext_vector_type(4)));

__device__ __forceinline__ unsigned pk2_(float a, float b) {
    unsigned ha = (unsigned)__builtin_bit_cast(unsigned short, (_Float16)a);
    unsigned hb = (unsigned)__builtin_bit_cast(unsigned short, (_Float16)b);
    return ha | (hb << 16);
}
__device__ __forceinline__ unsigned pkrtz_(float a, float b) {
    return __builtin_bit_cast(unsigned, __builtin_amdgcn_cvt_pkrtz(a, b));
}
__device__ __forceinline__ float flo_(float a) {   // a - f16(a)
    return a - (float)((_Float16)a);
}
__device__ __forceinline__ float sigmoidf_(float x) {
    return __builtin_amdgcn_rcpf(1.0f + __expf(-x));
}
__device__ __forceinline__ float tanhf_(float x) {
    x = fminf(fmaxf(x, -15.0f), 15.0f);
    float e = __expf(2.0f * x);
    return (e - 1.0f) * __builtin_amdgcn_rcpf(e + 1.0f);
}
#define MFMA16(a, b, c) __builtin_amdgcn_mfma_f32_16x16x32_f16((a), (b), (c), 0, 0, 0)

// lgkm-only barrier: does NOT drain vmcnt -> global prefetch regs survive
// across per-step barriers.
#define STEP_BARRIER() asm volatile("s_waitcnt lgkmcnt(0)\n\ts_barrier" ::: "memory")

// LDS strides (elements).
#define XST 40    // xh: per-(t,c) stride in f16 (80B, /16B = 5 odd)
#define HST 72    // hb: per-c stride in f16   (144B, /16B = 9 odd)
#define YST 65    // ya: per-(t,w) stride in f32

// R17 (R16 reverted; base = R15 @457us):
//  TWO independent GRU tiles per block. 512 threads / 8 waves: waves 0-3 run
//  tile A (batches bg*32..+15), waves 4-7 tile B (+16..+31). Each SIMD hosts
//  one wave of EACH tile; the HW scheduler fills tile A's stall slots
//  (~50% of the step: barrier + LDS + MFMA latency) with tile B's issue.
//  Per-tile code is bit-identical R15 -> absmax must be unchanged.
//  32 blocks; LDS ~86KB (1 WG/CU, fine at 32 blocks).
__global__ __launch_bounds__(512, 1) void brios_main(
    const float* __restrict__ x, const float* __restrict__ dt,
    const float* __restrict__ f_Wih, const float* __restrict__ f_Whh,
    const float* __restrict__ f_bih, const float* __restrict__ f_bhh,
    const float* __restrict__ f_gamma, const float* __restrict__ f_Wout,
    const float* __restrict__ f_bout,
    const float* __restrict__ b_Wih, const float* __restrict__ b_Whh,
    const float* __restrict__ b_bih, const float* __restrict__ b_bhh,
    const float* __restrict__ b_gamma, const float* __restrict__ b_Wout,
    const float* __restrict__ b_bout,
    float* __restrict__ out)
{
    const int tid  = threadIdx.x;
    const int w8   = tid >> 6;          // wave id 0..7
    const int tl   = w8 >> 2;           // tile 0/1 (by wave)
    const int w4   = w8 & 3;            // wave-in-tile 0..3
    const int lane = tid & 63;
    const int lr   = lane & 15;         // A row-in-tile / B,C column (batch)
    const int lg   = lane >> 4;         // k-octet group / C row-quad

    const int dir = blockIdx.x >> 4;    // 2 dirs x 16 groups of 32 batches
    const int bg  = blockIdx.x & 15;

    const float* Wih  = dir ? b_Wih  : f_Wih;
    const float* Whh  = dir ? b_Whh  : f_Whh;
    const float* bih  = dir ? b_bih  : f_bih;
    const float* bhh  = dir ? b_bhh  : f_bhh;
    const float* Wout = dir ? b_Wout : f_Wout;
    float gam = dir ? b_gamma[0] : f_gamma[0];
    gam = fminf(fmaxf(gam, 1e-4f), 10.0f);
    const float bo = dir ? b_bout[0] : f_bout[0];

    // staging coords: thread -> (tile, timestep, batch-in-tile)
    const int sTl = tid >> 8;                 // staging tile 0/1
    const int rem = tid & 255;
    const int tS  = rem >> 4, cS = rem & 15;
    const size_t bS = (size_t)bg * 32 + sTl * NB;   // staging batch base

    // ---- chunk x/dt register prefetch (double-buffered across chunks)
    float4 pv0, pv1, pv2, pv3;
    float pdt = 0.0f, pdt2 = 0.0f;
    auto PREF = [&](int cc) __attribute__((always_inline)) {
        int s  = cc * CH + tS;
        int tt = dir ? (LL - 1 - s) : s;
        const float* xp = x + ((bS + cS) * LL + tt) * DD;
        pv0 = ((const float4*)xp)[0];
        pv1 = ((const float4*)xp)[1];
        pv2 = ((const float4*)xp)[2];
        pv3 = ((const float4*)xp)[3];
        pdt = dt[(bS + cS) * LL + tt];
        int s2 = cc * CH + CH;
        if (rem < NB && s2 < LL) {
            int t2 = dir ? (LL - 1 - s2) : s2;
            pdt2 = dt[(bS + rem) * LL + t2];
        }
    };
    PREF(0);   // issue before the weight-load phase; overlaps it

    // ---- A fragments (weights), f16. Layout: row = lr, k = 8*lg + j.
    const int arow = 16 * w4 + lr;      // row within each 64-row gate block
    half8 AhR[2], AhZ[2], AhN[2];
#pragma unroll
    for (int kt = 0; kt < 2; ++kt)
#pragma unroll
        for (int j = 0; j < 8; ++j) {
            int k = kt * 32 + lg * 8 + j;
            AhR[kt][j] = (_Float16)Whh[(size_t)(arow      ) * HH + k];
            AhZ[kt][j] = (_Float16)Whh[(size_t)(arow +  64) * HH + k];
            AhN[kt][j] = (_Float16)Whh[(size_t)(arow + 128) * HH + k];
        }
    // x-side: K=32 where k<16 multiplies x_hi, k>=16 multiplies x_lo with the
    // SAME Wih column -> W*(x_hi + x_lo) = W*x at ~f32 input precision.
    half8 AxR, AxZ, AxN;
#pragma unroll
    for (int j = 0; j < 8; ++j) {
        int k = (lg * 8 + j) & 15;
        AxR[j] = (_Float16)Wih[(size_t)(arow      ) * DD + k];
        AxZ[j] = (_Float16)Wih[(size_t)(arow +  64) * DD + k];
        AxN[j] = (_Float16)Wih[(size_t)(arow + 128) * DD + k];
    }

    // ---- per-lane bias / wout (C layout: col=lr, rows rrow..rrow+3)
    const int rrow = 16 * w4 + 4 * lg;
    f32x4 bR, bZ, bNX, bNH;
    float wo4[4];
#pragma unroll
    for (int j = 0; j < 4; ++j) {
        bR[j]  = bih[rrow + j]       + bhh[rrow + j];
        bZ[j]  = bih[64 + rrow + j]  + bhh[64 + rrow + j];
        bNX[j] = bih[128 + rrow + j];
        bNH[j] = bhh[128 + rrow + j];
        wo4[j] = Wout[rrow + j];
    }

    __shared__ alignas(16) _Float16 xh[2][CH][NB][XST];  // x B-frags per tile
    __shared__ alignas(16) _Float16 hb[2][2][NB][HST];   // hbar B-frags, dbuf
    __shared__ float dcy[2][CH + 1][NB];                 // decay per (t, batch)
    __shared__ float ya[2][CH][4][YST];                  // per-wave y partials

    // ---- init hbar(0) = 0 (each tile's 4 waves cover all its rows;
    //      visibility gated by the first staging barrier)
    *(uint2*)&hb[tl][0][lr][rrow] = make_uint2(0u, 0u);
    f32x4 hb4 = {0.f, 0.f, 0.f, 0.f};                    // own rows' hbar, f32

    float* yd = out + (size_t)(1 + dir) * (BB * LL);

    // x-gate accumulators, ping-pong (computed one step ahead)
    f32x4 xrA, xzA, xnA, xrB, xzB, xnB;

    // one GRU step (bit-identical R15 math). Consumes x-accs for step lt;
    // prefetches Bx(lt+1) and issues its x-MFMAs — off the chain.
    auto STEP = [&](int lt,
                    f32x4& xrC, f32x4& xzC, f32x4& xnC,
                    f32x4& xrN, f32x4& xzN, f32x4& xnN)
                    __attribute__((always_inline)) {
        const int rb = lt & 1;
        // chain-critical reads first
        half8 Bh0 = *(const half8*)&hb[tl][rb][lr][lg * 8];
        half8 Bh1 = *(const half8*)&hb[tl][rb][lr][32 + lg * 8];
        float dnx = dcy[tl][lt + 1][lr];
        int nx = (lt + 1 < CH) ? lt + 1 : lt;          // clamp (last is dummy)
        half8 BxN = *(const half8*)&xh[tl][nx][lr][lg * 8];

        // h-MFMAs chained on the prefetched x-accs (R15 order)
        f32x4 aR  = MFMA16(AhR[0], Bh0, xrC);
        f32x4 aNH = MFMA16(AhN[0], Bh0, bNH);
        f32x4 aZ  = MFMA16(AhZ[0], Bh0, xzC);
        aR  = MFMA16(AhR[1], Bh1, aR);
        aNH = MFMA16(AhN[1], Bh1, aNH);
        aZ  = MFMA16(AhZ[1], Bh1, aZ);

        // next step's x-MFMAs (independent regs, consumed next step)
        xrN = MFMA16(AxR, BxN, bR);
        xzN = MFMA16(AxZ, BxN, bZ);
        xnN = MFMA16(AxN, BxN, bNX);

        f32x4 hnew, hbn;
#pragma unroll
        for (int j = 0; j < 4; ++j) {
            float r  = sigmoidf_(aR[j]);
            float zz = sigmoidf_(aZ[j]);
            float n  = tanhf_(xnC[j] + r * aNH[j]);
            hnew[j] = n + zz * (hb4[j] - n);
            hbn[j]  = hnew[j] * dnx;
        }

        // critical tail: pack + write next hbar
        unsigned p0 = pkrtz_(hbn[0], hbn[1]);
        unsigned p1 = pkrtz_(hbn[2], hbn[3]);
        *(uint2*)&hb[tl][rb ^ 1][lr][rrow] = make_uint2(p0, p1);
        hb4 = hbn;

        // y partial (off-chain)
        float sy = wo4[0] * hnew[0] + wo4[1] * hnew[1]
                 + wo4[2] * hnew[2] + wo4[3] * hnew[3];
        ya[tl][lt][w4][lane] = sy;

        STEP_BARRIER();
    };

#pragma unroll 1
    for (int c0 = 0; c0 < LL / CH; ++c0) {
        const int s0 = c0 * CH;

        // ---- stage x (hi/lo f16) and decay from the prefetched registers
        {
            float vv[16];
            *(float4*)(vv + 0)  = pv0;
            *(float4*)(vv + 4)  = pv1;
            *(float4*)(vv + 8)  = pv2;
            *(float4*)(vv + 12) = pv3;
            unsigned uh[8], ul[8];
#pragma unroll
            for (int d = 0; d < 8; ++d) {
                float a = vv[2 * d], b2 = vv[2 * d + 1];
                uh[d] = pk2_(a, b2);
                ul[d] = pk2_(flo_(a), flo_(b2));
            }
            *(uint4*)&xh[sTl][tS][cS][0]  = make_uint4(uh[0], uh[1], uh[2], uh[3]);
            *(uint4*)&xh[sTl][tS][cS][8]  = make_uint4(uh[4], uh[5], uh[6], uh[7]);
            *(uint4*)&xh[sTl][tS][cS][16] = make_uint4(ul[0], ul[1], ul[2], ul[3]);
            *(uint4*)&xh[sTl][tS][cS][24] = make_uint4(ul[4], ul[5], ul[6], ul[7]);

            float dv = fminf(fmaxf(pdt, 0.0f), 1e6f);
            dcy[sTl][tS][cS] = __expf(-gam * dv);
            if (rem < NB) {                    // one-past-chunk decay
                float d = 0.0f;
                if (s0 + CH < LL) {
                    float dv2 = fminf(fmaxf(pdt2, 0.0f), 1e6f);
                    d = __expf(-gam * dv2);
                }
                dcy[sTl][CH][rem] = d;
            }
        }
        STEP_BARRIER();

        // ---- issue NEXT chunk's global loads; stay outstanding across the
        //      step barriers (lgkm-only), consumed at next chunk's staging
        if (c0 + 1 < LL / CH) PREF(c0 + 1);

        // ---- preload step 0's x-gates
        {
            half8 Bx0 = *(const half8*)&xh[tl][0][lr][lg * 8];
            xrA = MFMA16(AxR, Bx0, bR);
            xzA = MFMA16(AxZ, Bx0, bZ);
            xnA = MFMA16(AxN, Bx0, bNX);
        }

        // ---- recurrent steps (manual 2-unroll, ping-pong x-accs)
#pragma unroll 1
        for (int lt = 0; lt < CH; lt += 2) {
            STEP(lt,     xrA, xzA, xnA, xrB, xzB, xnB);
            STEP(lt + 1, xrB, xzB, xnB, xrA, xzA, xnA);
        }

        // ---- y: reduce 16 partials per (tile, t, batch), store
        {
            int lt2 = rem & 15, c2 = rem >> 4;
            float sacc = 0.0f;
#pragma unroll
            for (int w2 = 0; w2 < 4; ++w2)
#pragma unroll
                for (int g = 0; g < 4; ++g)
                    sacc += ya[sTl][lt2][w2][g * 16 + c2];
            int s  = s0 + lt2;
            int tt = dir ? (LL - 1 - s) : s;
            yd[(bS + c2) * LL + tt] = sacc + bo;
        }
        // no trailing barrier: next staging writes xh/dcy (not read anymore),
        // its own barrier gates the next chunk's reads.
    }
}

__global__ __launch_bounds__(256) void brios_avg(float* __restrict__ out)
{
    int i = blockIdx.x * blockDim.x + threadIdx.x;
    const int n4 = (BB * LL) / 4;
    if (i < n4) {
        const float4* yf = (const float4*)(out + (size_t)BB * LL);
        const float4* yb = (const float4*)(out + (size_t)2 * BB * LL);
        float4 a = yf[i], b2 = yb[i];
        float4 r;
        r.x = 0.5f * (a.x + b2.x);
        r.y = 0.5f * (a.y + b2.y);
        r.z = 0.5f * (a.z + b2.z);
        r.w = 0.5f * (a.w + b2.w);
        ((float4*)out)[i] = r;
    }
}

extern "C" void kernel_launch(void* const* d_in, const int* in_sizes, int n_in,
                              void* d_out, int out_size, void* d_ws, size_t ws_size,
                              hipStream_t stream) {
    const float* x       = (const float*)d_in[0];
    const float* dt      = (const float*)d_in[1];
    const float* f_Wih   = (const float*)d_in[2];
    const float* f_Whh   = (const float*)d_in[3];
    const float* f_bih   = (const float*)d_in[4];
    const float* f_bhh   = (const float*)d_in[5];
    const float* f_gamma = (const float*)d_in[6];
    const float* f_Wout  = (const float*)d_in[7];
    const float* f_bout  = (const float*)d_in[8];
    const float* b_Wih   = (const float*)d_in[9];
    const float* b_Whh   = (const float*)d_in[10];
    const float* b_bih   = (const float*)d_in[11];
    const float* b_bhh   = (const float*)d_in[12];
    const float* b_gamma = (const float*)d_in[13];
    const float* b_Wout  = (const float*)d_in[14];
    const float* b_bout  = (const float*)d_in[15];
    float* out = (float*)d_out;

    brios_main<<<32, 512, 0, stream>>>(x, dt,
        f_Wih, f_Whh, f_bih, f_bhh, f_gamma, f_Wout, f_bout,
        b_Wih, b_Whh, b_bih, b_bhh, b_gamma, b_Wout, b_bout, out);

    const int n4 = (BB * LL) / 4;
    brios_avg<<<(n4 + 255) / 256, 256, 0, stream>>>(out);
}

// Round 7
// 514.366 us; speedup vs baseline: 1.4547x; 1.4547x over previous
//
#include <hip/hip_runtime.h>

#define BB 512
#define LL 1024
#define DD 16
#define HH 64
#define CH 16     // timesteps per chunk
#define NB 16     // batches per block (MFMA N)
#define NC (LL / CH)

typedef _Float16 half8 __attribute__((ext_vector_type(8)));
typedef float    f32x4 __attribute__((ext_vector_type(4)));

__device__ __forceinline__ unsigned pk2_(float a, float b) {
    unsigned ha = (unsigned)__builtin_bit_cast(unsigned short, (_Float16)a);
    unsigned hb = (unsigned)__builtin_bit_cast(unsigned short, (_Float16)b);
    return ha | (hb << 16);
}
__device__ __forceinline__ unsigned pkrtz_(float a, float b) {
    return __builtin_bit_cast(unsigned, __builtin_amdgcn_cvt_pkrtz(a, b));
}
__device__ __forceinline__ float flo_(float a) {   // a - f16(a)
    return a - (float)((_Float16)a);
}
#define MFMA16(a, b, c) __builtin_amdgcn_mfma_f32_16x16x32_f16((a), (b), (c), 0, 0, 0)

// lgkm-only barrier: does NOT drain vmcnt -> global prefetch regs survive
// across per-step barriers.
#define STEP_BARRIER() asm volatile("s_waitcnt lgkmcnt(0)\n\ts_barrier" ::: "memory")

// LDS strides (elements).
#define XST 40    // xh: per-(t,c) stride in f16 (80B = 5 slots, odd)
#define HST 88    // hb: per-c stride in f16 (176B = 11 slots odd, 16B-aligned)
#define YST 65    // ya: per-(t,w) stride in f32

// R19 (base = R15 @457us; R16 full-unroll and R17 2-tile both reverted):
//  - rcp pairing: r/z sigmoids share one rcp per j (common denominator);
//    the two tanh rcps pair across j. 12 -> 6 rcps/step (trans is the
//    most expensive instr class at quarter rate).
//  - chunk-boundary bubble removed: xh/dcy/ya double-buffered by chunk
//    parity; staging of chunk c+1 runs mid-chunk (between steps 8/9) from
//    prefetched registers; no dedicated staging barrier (step barriers
//    provide the ordering); STEP(15) prefetches next-chunk x directly.
//  - hb stride 72->88 f16: odd-dword slot stride kills the 8-bank aliasing
//    (SQ_LDS_BANK_CONFLICT 5.5M).
__global__ __launch_bounds__(256, 1) void brios_main(
    const float* __restrict__ x, const float* __restrict__ dt,
    const float* __restrict__ f_Wih, const float* __restrict__ f_Whh,
    const float* __restrict__ f_bih, const float* __restrict__ f_bhh,
    const float* __restrict__ f_gamma, const float* __restrict__ f_Wout,
    const float* __restrict__ f_bout,
    const float* __restrict__ b_Wih, const float* __restrict__ b_Whh,
    const float* __restrict__ b_bih, const float* __restrict__ b_bhh,
    const float* __restrict__ b_gamma, const float* __restrict__ b_Wout,
    const float* __restrict__ b_bout,
    float* __restrict__ out)
{
    const int tid  = threadIdx.x;
    const int w    = tid >> 6;          // wave id 0..3
    const int lane = tid & 63;
    const int lr   = lane & 15;         // A row-in-tile / B,C column (batch)
    const int lg   = lane >> 4;         // k-octet group / C row-quad

    const int dir = blockIdx.x >> 5;    // 2 dirs x 32 groups
    const int bg  = blockIdx.x & 31;

    const float* Wih  = dir ? b_Wih  : f_Wih;
    const float* Whh  = dir ? b_Whh  : f_Whh;
    const float* bih  = dir ? b_bih  : f_bih;
    const float* bhh  = dir ? b_bhh  : f_bhh;
    const float* Wout = dir ? b_Wout : f_Wout;
    float gam = dir ? b_gamma[0] : f_gamma[0];
    gam = fminf(fmaxf(gam, 1e-4f), 10.0f);
    const float bo = dir ? b_bout[0] : f_bout[0];

    const int tS = tid >> 4, cS = tid & 15;            // staging coords
    const size_t bB = (size_t)bg * NB;                 // first batch of block

    // ---- chunk x/dt register prefetch (double-buffered across chunks)
    float4 pv0, pv1, pv2, pv3;
    float pdt = 0.0f;
    auto PREF = [&](int cc) __attribute__((always_inline)) {
        int s  = cc * CH + tS;
        int tt = dir ? (LL - 1 - s) : s;
        const float* xp = x + ((bB + cS) * LL + tt) * DD;
        pv0 = ((const float4*)xp)[0];
        pv1 = ((const float4*)xp)[1];
        pv2 = ((const float4*)xp)[2];
        pv3 = ((const float4*)xp)[3];
        pdt = dt[(bB + cS) * LL + tt];
    };
    PREF(0);   // issue before the weight-load phase; overlaps it

    // ---- A fragments (weights), f16. Layout: row = lr, k = 8*lg + j.
    const int arow = 16 * w + lr;       // row within each 64-row gate block
    half8 AhR[2], AhZ[2], AhN[2];
#pragma unroll
    for (int kt = 0; kt < 2; ++kt)
#pragma unroll
        for (int j = 0; j < 8; ++j) {
            int k = kt * 32 + lg * 8 + j;
            AhR[kt][j] = (_Float16)Whh[(size_t)(arow      ) * HH + k];
            AhZ[kt][j] = (_Float16)Whh[(size_t)(arow +  64) * HH + k];
            AhN[kt][j] = (_Float16)Whh[(size_t)(arow + 128) * HH + k];
        }
    // x-side: K=32 where k<16 multiplies x_hi, k>=16 multiplies x_lo with the
    // SAME Wih column -> W*(x_hi + x_lo) = W*x at ~f32 input precision.
    half8 AxR, AxZ, AxN;
#pragma unroll
    for (int j = 0; j < 8; ++j) {
        int k = (lg * 8 + j) & 15;
        AxR[j] = (_Float16)Wih[(size_t)(arow      ) * DD + k];
        AxZ[j] = (_Float16)Wih[(size_t)(arow +  64) * DD + k];
        AxN[j] = (_Float16)Wih[(size_t)(arow + 128) * DD + k];
    }

    // ---- per-lane bias / wout (C layout: col=lr, rows rrow..rrow+3)
    const int rrow = 16 * w + 4 * lg;
    f32x4 bR, bZ, bNX, bNH;
    float wo4[4];
#pragma unroll
    for (int j = 0; j < 4; ++j) {
        bR[j]  = bih[rrow + j]       + bhh[rrow + j];
        bZ[j]  = bih[64 + rrow + j]  + bhh[64 + rrow + j];
        bNX[j] = bih[128 + rrow + j];
        bNH[j] = bhh[128 + rrow + j];
        wo4[j] = Wout[rrow + j];
    }

    __shared__ alignas(16) _Float16 xh[2][CH][NB][XST];  // x B-frags, chunk-par
    __shared__ alignas(16) _Float16 hb[2][NB][HST];      // hbar B-frags, step-par
    __shared__ float dcy[2][CH][NB];                     // decay, chunk-par
    __shared__ float ya[2][CH][4][YST];                  // y partials, chunk-par

    // ---- stage chunk 0 (from prefetched regs) + init hbar(0)=0
    auto STAGE = [&](int pp) __attribute__((always_inline)) {
        float vv[16];
        *(float4*)(vv + 0)  = pv0;
        *(float4*)(vv + 4)  = pv1;
        *(float4*)(vv + 8)  = pv2;
        *(float4*)(vv + 12) = pv3;
        unsigned uh[8], ul[8];
#pragma unroll
        for (int d = 0; d < 8; ++d) {
            float a = vv[2 * d], b2 = vv[2 * d + 1];
            uh[d] = pk2_(a, b2);
            ul[d] = pk2_(flo_(a), flo_(b2));
        }
        *(uint4*)&xh[pp][tS][cS][0]  = make_uint4(uh[0], uh[1], uh[2], uh[3]);
        *(uint4*)&xh[pp][tS][cS][8]  = make_uint4(uh[4], uh[5], uh[6], uh[7]);
        *(uint4*)&xh[pp][tS][cS][16] = make_uint4(ul[0], ul[1], ul[2], ul[3]);
        *(uint4*)&xh[pp][tS][cS][24] = make_uint4(ul[4], ul[5], ul[6], ul[7]);
        float dv = fminf(fmaxf(pdt, 0.0f), 1e6f);
        dcy[pp][tS][cS] = __expf(-gam * dv);
    };
    STAGE(0);
    *(uint2*)&hb[0][lr][rrow] = make_uint2(0u, 0u);
    f32x4 hb4 = {0.f, 0.f, 0.f, 0.f};                    // own rows' hbar, f32
    STEP_BARRIER();
    PREF(1);

    float* yd = out + (size_t)(1 + dir) * (BB * LL);

    // x-gate accumulators, ping-pong (computed one step ahead)
    f32x4 xrA, xzA, xnA, xrB, xzB, xnB;
    {   // preload step 0's x-gates (chunk 0)
        half8 Bx0 = *(const half8*)&xh[0][0][lr][lg * 8];
        xrA = MFMA16(AxR, Bx0, bR);
        xzA = MFMA16(AxZ, Bx0, bZ);
        xnA = MFMA16(AxN, Bx0, bNX);
    }

    // one GRU step. Consumes x-accs for step lt of chunk parity p; prefetches
    // the NEXT step's Bx/x-MFMAs (crossing into chunk parity 1-p at lt=15).
    auto STEP = [&](int lt, int p,
                    f32x4& xrC, f32x4& xzC, f32x4& xnC,
                    f32x4& xrN, f32x4& xzN, f32x4& xnN)
                    __attribute__((always_inline)) {
        const int rb = lt & 1;
        const int np = (lt < CH - 1) ? p : 1 - p;      // next-step buffers
        const int ni = (lt < CH - 1) ? lt + 1 : 0;
        // chain-critical reads first
        half8 Bh0 = *(const half8*)&hb[rb][lr][lg * 8];
        half8 Bh1 = *(const half8*)&hb[rb][lr][32 + lg * 8];
        float dnx = dcy[np][ni][lr];
        half8 BxN = *(const half8*)&xh[np][ni][lr][lg * 8];

        // h-MFMAs chained on the prefetched x-accs
        f32x4 aR  = MFMA16(AhR[0], Bh0, xrC);
        f32x4 aNH = MFMA16(AhN[0], Bh0, bNH);
        f32x4 aZ  = MFMA16(AhZ[0], Bh0, xzC);
        aR  = MFMA16(AhR[1], Bh1, aR);
        aNH = MFMA16(AhN[1], Bh1, aNH);
        aZ  = MFMA16(AhZ[1], Bh1, aZ);

        // next step's x-MFMAs (independent regs, consumed next step)
        xrN = MFMA16(AxR, BxN, bR);
        xzN = MFMA16(AxZ, BxN, bZ);
        xnN = MFMA16(AxN, BxN, bNX);

        // activations: r/z share one rcp per j; tanh rcps pair across j
        float rr[4], zz[4], e2[4];
#pragma unroll
        for (int j = 0; j < 4; ++j) {
            float er = __expf(-aR[j]);
            float ez = __expf(-aZ[j]);
            float pr = 1.0f + er, pz = 1.0f + ez;
            float inv = __builtin_amdgcn_rcpf(pr * pz);
            rr[j] = pz * inv;                    // sigmoid(aR)
            zz[j] = pr * inv;                    // sigmoid(aZ)
        }
#pragma unroll
        for (int j = 0; j < 4; ++j) {
            float targ = xnC[j] + rr[j] * aNH[j];
            targ = fminf(fmaxf(targ, -15.0f), 15.0f);
            e2[j] = __expf(2.0f * targ);
        }
        f32x4 hnew, hbn;
#pragma unroll
        for (int jp = 0; jp < 2; ++jp) {
            int j0 = 2 * jp, j1 = 2 * jp + 1;
            float q0 = e2[j0] + 1.0f, q1 = e2[j1] + 1.0f;
            float inv = __builtin_amdgcn_rcpf(q0 * q1);
            float n0 = (e2[j0] - 1.0f) * (q1 * inv);   // tanh j0
            float n1 = (e2[j1] - 1.0f) * (q0 * inv);   // tanh j1
            hnew[j0] = n0 + zz[j0] * (hb4[j0] - n0);
            hnew[j1] = n1 + zz[j1] * (hb4[j1] - n1);
            hbn[j0]  = hnew[j0] * dnx;
            hbn[j1]  = hnew[j1] * dnx;
        }

        // critical tail: pack + write next hbar
        unsigned p0 = pkrtz_(hbn[0], hbn[1]);
        unsigned p1 = pkrtz_(hbn[2], hbn[3]);
        *(uint2*)&hb[rb ^ 1][lr][rrow] = make_uint2(p0, p1);
        hb4 = hbn;

        // y partial (off-chain)
        float sy = wo4[0] * hnew[0] + wo4[1] * hnew[1]
                 + wo4[2] * hnew[2] + wo4[3] * hnew[3];
        ya[p][lt][w][lane] = sy;

        STEP_BARRIER();
    };

#pragma unroll 1
    for (int c0 = 0; c0 < NC; ++c0) {
        const int p = c0 & 1;

        // ---- recurrent steps (manual 2-unroll, ping-pong x-accs);
        //      mid-chunk: stage chunk c0+1 + prefetch chunk c0+2
#pragma unroll 1
        for (int lt = 0; lt < CH; lt += 2) {
            STEP(lt, p, xrA, xzA, xnA, xrB, xzB, xnB);
            if (lt == 8 && c0 + 1 < NC) {
                STAGE(1 - p);
                if (c0 + 2 < NC) PREF(c0 + 2);
            }
            STEP(lt + 1, p, xrB, xzB, xnB, xrA, xzA, xnA);
        }

        // ---- y: reduce 16 partials per (t, batch), store
        //      (safe: gated by step-15's barrier; next chunk writes ya[1-p])
        {
            int lt2 = tid & 15, c2 = tid >> 4;
            float sacc = 0.0f;
#pragma unroll
            for (int w2 = 0; w2 < 4; ++w2)
#pragma unroll
                for (int g = 0; g < 4; ++g)
                    sacc += ya[p][lt2][w2][g * 16 + c2];
            int s  = c0 * CH + lt2;
            int tt = dir ? (LL - 1 - s) : s;
            yd[(bB + c2) * LL + tt] = sacc + bo;
        }
    }
}

__global__ __launch_bounds__(256) void brios_avg(float* __restrict__ out)
{
    int i = blockIdx.x * blockDim.x + threadIdx.x;
    const int n4 = (BB * LL) / 4;
    if (i < n4) {
        const float4* yf = (const float4*)(out + (size_t)BB * LL);
        const float4* yb = (const float4*)(out + (size_t)2 * BB * LL);
        float4 a = yf[i], b2 = yb[i];
        float4 r;
        r.x = 0.5f * (a.x + b2.x);
        r.y = 0.5f * (a.y + b2.y);
        r.z = 0.5f * (a.z + b2.z);
        r.w = 0.5f * (a.w + b2.w);
        ((float4*)out)[i] = r;
    }
}

extern "C" void kernel_launch(void* const* d_in, const int* in_sizes, int n_in,
                              void* d_out, int out_size, void* d_ws, size_t ws_size,
                              hipStream_t stream) {
    const float* x       = (const float*)d_in[0];
    const float* dt      = (const float*)d_in[1];
    const float* f_Wih   = (const float*)d_in[2];
    const float* f_Whh   = (const float*)d_in[3];
    const float* f_bih   = (const float*)d_in[4];
    const float* f_bhh   = (const float*)d_in[5];
    const float* f_gamma = (const float*)d_in[6];
    const float* f_Wout  = (const float*)d_in[7];
    const float* f_bout  = (const float*)d_in[8];
    const float* b_Wih   = (const float*)d_in[9];
    const float* b_Whh   = (const float*)d_in[10];
    const float* b_bih   = (const float*)d_in[11];
    const float* b_bhh   = (const float*)d_in[12];
    const float* b_gamma = (const float*)d_in[13];
    const float* b_Wout  = (const float*)d_in[14];
    const float* b_bout  = (const float*)d_in[15];
    float* out = (float*)d_out;

    brios_main<<<64, 256, 0, stream>>>(x, dt,
        f_Wih, f_Whh, f_bih, f_bhh, f_gamma, f_Wout, f_bout,
        b_Wih, b_Whh, b_bih, b_bhh, b_gamma, b_Wout, b_bout, out);

    const int n4 = (BB * LL) / 4;
    brios_avg<<<(n4 + 255) / 256, 256, 0, stream>>>(out);
}